// Round 1
// baseline (445.559 us; speedup 1.0000x reference)
//
#include <hip/hip_runtime.h>

// LinkPredictor: score[e] = w2 . relu(W1 . concat(h[src[e]], h[dst[e]]) + b1) + b2
// N_NODES=100000, N_EDGES=1600000, D=128, K2=256, H=256

#define NNODES 100000
#define E_TOTAL 1600000
#define D 128
#define K2 256
#define H 256

#define TILE_M 64
#define LDSROW 264          // 256 + 8 bf16 pad -> row stride 132 dwords (132%32=4): 2-way max aliasing (free)
#define NTILES (E_TOTAL / TILE_M)   // 25000
#define GRID 2500                   // 10 tiles per block, exact

typedef short bf16x8 __attribute__((ext_vector_type(8)));
typedef float f32x4 __attribute__((ext_vector_type(4)));

__device__ __forceinline__ unsigned short f2bf(float f) {
    unsigned u = __float_as_uint(f);
    u += 0x7fff + ((u >> 16) & 1);   // round-to-nearest-even
    return (unsigned short)(u >> 16);
}

__global__ void cvt_kernel(const float* __restrict__ src, unsigned short* __restrict__ dst, int n4) {
    int i = blockIdx.x * blockDim.x + threadIdx.x;
    if (i >= n4) return;
    float4 v = ((const float4*)src)[i];
    ushort4 o;
    o.x = f2bf(v.x); o.y = f2bf(v.y); o.z = f2bf(v.z); o.w = f2bf(v.w);
    ((ushort4*)dst)[i] = o;
}

// Each block: 256 threads = 4 waves. Wave w owns hidden cols [64w, 64w+64).
// W1 slice (64x256 bf16 = 128 VGPRs) preloaded once; grid-stride over edge tiles.
__global__ __launch_bounds__(256, 2) void edge_mlp(
    const unsigned short* __restrict__ hbf,
    const int* __restrict__ srcE,
    const int* __restrict__ dstE,
    const unsigned short* __restrict__ w1bf,
    const float* __restrict__ b1,
    const float* __restrict__ w2,
    const float* __restrict__ b2p,
    float* __restrict__ out)
{
    __shared__ unsigned short X[TILE_M * LDSROW];   // 33792 B
    __shared__ float red[TILE_M][4];                // cross-wave score partials

    const int tid = threadIdx.x;
    const int wave = tid >> 6;
    const int lane = tid & 63;
    const int lane15 = lane & 15;
    const int quad = lane >> 4;

    // --- preload B fragments: B[k][n] = W1[n][k]; lane holds W1[n=lane15-based][k..k+7] (contig) ---
    bf16x8 B[8][4];
#pragma unroll
    for (int kit = 0; kit < 8; ++kit) {
#pragma unroll
        for (int nt = 0; nt < 4; ++nt) {
            int n = wave * 64 + nt * 16 + lane15;
            int k = kit * 32 + quad * 8;
            B[kit][nt] = *(const bf16x8*)(w1bf + n * K2 + k);
        }
    }

    float b1v[4], w2v[4];
#pragma unroll
    for (int nt = 0; nt < 4; ++nt) {
        int n = wave * 64 + nt * 16 + lane15;
        b1v[nt] = b1[n];
        w2v[nt] = w2[n];
    }
    const float b2 = *b2p;

    const int ghalf = tid >> 4;   // 0..15: which 128-feature half-row this thread gathers
    const int gl = tid & 15;      // 16 lanes x 16B = one contiguous 256B half-row

    for (int tile = blockIdx.x; tile < NTILES; tile += GRID) {
        const int ebase = tile * TILE_M;

        __syncthreads();   // previous tile's X reads + red reads complete
        // --- gather 64 edges x 256 bf16 into LDS ---
#pragma unroll 4
        for (int it = 0; it < 8; ++it) {
            int hh = it * 16 + ghalf;                  // 0..127 half-rows
            int e = ebase + (hh >> 1);
            int node = (hh & 1) ? dstE[e] : srcE[e];
            bf16x8 v = *(const bf16x8*)(hbf + node * D + gl * 8);
            *(bf16x8*)&X[(hh >> 1) * LDSROW + (hh & 1) * D + gl * 8] = v;
        }
        __syncthreads();

        // --- MFMA: hid[64 x 64-slice] ---
        f32x4 acc[4][4];
        const f32x4 zero = {0.f, 0.f, 0.f, 0.f};
#pragma unroll
        for (int ms = 0; ms < 4; ++ms)
#pragma unroll
            for (int nt = 0; nt < 4; ++nt)
                acc[ms][nt] = zero;

#pragma unroll
        for (int kit = 0; kit < 8; ++kit) {
            bf16x8 a[4];
#pragma unroll
            for (int ms = 0; ms < 4; ++ms)
                a[ms] = *(const bf16x8*)&X[(ms * 16 + lane15) * LDSROW + kit * 32 + quad * 8];
#pragma unroll
            for (int ms = 0; ms < 4; ++ms)
#pragma unroll
                for (int nt = 0; nt < 4; ++nt)
                    acc[ms][nt] = __builtin_amdgcn_mfma_f32_16x16x32_bf16(
                        a[ms], B[kit][nt], acc[ms][nt], 0, 0, 0);
        }

        // --- fused epilogue: bias + relu + dot(w2), per-row reduce ---
        // C/D layout: col n = nt*16 + lane15, row m = quad*4 + r (within ms subtile)
#pragma unroll
        for (int ms = 0; ms < 4; ++ms) {
#pragma unroll
            for (int r = 0; r < 4; ++r) {
                float p = 0.f;
#pragma unroll
                for (int nt = 0; nt < 4; ++nt) {
                    float hv = acc[ms][nt][r] + b1v[nt];
                    p = fmaf(fmaxf(hv, 0.f), w2v[nt], p);
                }
                p += __shfl_xor(p, 1, 16);
                p += __shfl_xor(p, 2, 16);
                p += __shfl_xor(p, 4, 16);
                p += __shfl_xor(p, 8, 16);
                if (lane15 == 0) red[ms * 16 + quad * 4 + r][wave] = p;
            }
        }
        __syncthreads();
        if (tid < TILE_M) {
            float s = red[tid][0] + red[tid][1] + red[tid][2] + red[tid][3] + b2;
            out[ebase + tid] = s;
        }
    }
}

extern "C" void kernel_launch(void* const* d_in, const int* in_sizes, int n_in,
                              void* d_out, int out_size, void* d_ws, size_t ws_size,
                              hipStream_t stream) {
    const float* h    = (const float*)d_in[0];
    const int*   srcE = (const int*)d_in[1];
    const int*   dstE = (const int*)d_in[2];
    const float* W1   = (const float*)d_in[3];
    const float* b1   = (const float*)d_in[4];
    const float* w2   = (const float*)d_in[5];
    const float* b2   = (const float*)d_in[6];
    float* out = (float*)d_out;

    unsigned short* hbf  = (unsigned short*)d_ws;               // 100000*128*2 = 25.6 MB
    unsigned short* w1bf = hbf + (size_t)NNODES * D;            // 256*256*2 = 128 KB

    int n4h = NNODES * D / 4;   // 3,200,000 float4 groups
    cvt_kernel<<<(n4h + 255) / 256, 256, 0, stream>>>(h, hbf, n4h);
    int n4w = H * K2 / 4;       // 16384
    cvt_kernel<<<(n4w + 255) / 256, 256, 0, stream>>>(W1, w1bf, n4w);

    edge_mlp<<<GRID, 256, 0, stream>>>(hbf, srcE, dstE, w1bf, b1, w2, b2, out);
}